// Round 3
// baseline (284.743 us; speedup 1.0000x reference)
//
#include <hip/hip_runtime.h>
#include <cstdint>

// Problem constants (reference: B,J,D,W,H,EH,L = 128,8192,32,4,128,256,32)
#define BDIM 128
#define JDIM 8192

typedef short s8x __attribute__((ext_vector_type(8)));   // 8 bf16 in 4 VGPRs (MFMA A/B frag)
typedef float f4x __attribute__((ext_vector_type(4)));   // MFMA C/D frag

__device__ __forceinline__ unsigned int rne16(float f) {
    unsigned int u = __float_as_uint(f);
    return (u + 0x7fffu + ((u >> 16) & 1u)) >> 16;       // round-to-nearest-even bf16
}
__device__ __forceinline__ unsigned int pkbf(float lo, float hi) {
    return rne16(lo) | (rne16(hi) << 16);
}
__device__ __forceinline__ float bf2f(unsigned int s) {
    return __uint_as_float(s << 16);
}

// 16-lane (DPP-row) all-reduce sum: xor1, xor2, ^7, ^15 — pure VALU, no DS pipe.
template <int CTRL>
__device__ __forceinline__ float dppadd(float x) {
    int y = __builtin_amdgcn_update_dpp(0, __builtin_bit_cast(int, x), CTRL, 0xF, 0xF, true);
    return x + __builtin_bit_cast(float, y);
}
__device__ __forceinline__ float allred16(float x) {
    x = dppadd<0xB1>(x);    // quad_perm [1,0,3,2]  : lane ^ 1
    x = dppadd<0x4E>(x);    // quad_perm [2,3,0,1]  : lane ^ 2
    x = dppadd<0x141>(x);   // row_half_mirror      : lane ^ 7
    x = dppadd<0x140>(x);   // row_mirror           : lane ^ 15
    return x;
}

// ---------------------------------------------------------------------------
// Kernel 0: feW[j][h] = fe[j,:] @ h_w1[1:,:] + h_b1  (stored bf16), plus per-j
// moments for closed-form LN1 stats; block j==0 writes mean(w0), mean(w0^2).
// ---------------------------------------------------------------------------
__global__ __launch_bounds__(128) void k_prep(
    const float* __restrict__ fe, const float* __restrict__ hw1,
    const float* __restrict__ hb1,
    unsigned short* __restrict__ feWb, float* __restrict__ aux,
    float* __restrict__ scal)
{
    const int j = blockIdx.x, h = threadIdx.x;
    float acc = hb1[h];
#pragma unroll
    for (int d = 0; d < 32; ++d)
        acc = fmaf(fe[j * 32 + d], hw1[(1 + d) * 128 + h], acc);
    feWb[(size_t)j * 128 + h] = (unsigned short)rne16(acc);

    const float w0h = hw1[h];
    float s1 = acc, sx = w0h * acc, s2 = acc * acc;
#pragma unroll
    for (int m = 1; m <= 32; m <<= 1) {
        s1 += __shfl_xor(s1, m); sx += __shfl_xor(sx, m); s2 += __shfl_xor(s2, m);
    }
    __shared__ float red[2][3];
    const int wv = threadIdx.x >> 6, ln = threadIdx.x & 63;
    if (ln == 0) { red[wv][0] = s1; red[wv][1] = sx; red[wv][2] = s2; }
    __syncthreads();
    if (threadIdx.x == 0) {
        aux[j * 4 + 0] = (red[0][0] + red[1][0]) * (1.f / 128.f);
        aux[j * 4 + 1] = (red[0][1] + red[1][1]) * (1.f / 128.f);
        aux[j * 4 + 2] = (red[0][2] + red[1][2]) * (1.f / 128.f);
    }
    if (j == 0) {
        float a = w0h, b = w0h * w0h;
#pragma unroll
        for (int m = 1; m <= 32; m <<= 1) { a += __shfl_xor(a, m); b += __shfl_xor(b, m); }
        __syncthreads();
        if (ln == 0) { red[wv][0] = a; red[wv][1] = b; }
        __syncthreads();
        if (threadIdx.x == 0) {
            scal[0] = (red[0][0] + red[1][0]) * (1.f / 128.f);
            scal[1] = (red[0][1] + red[1][1]) * (1.f / 128.f);
        }
    }
}

// ---------------------------------------------------------------------------
// Kernel 1: per cell (b,j): pre -> LN1 -> relu -> (MFMA) @h_w2 -> +b2 -> LN2
// -> relu -> gates (MFMA + DPP all-reduce) -> exp(logit-10) -> weighted
// accumulation of head_sums in registers.  Wave = 1 j x 16 b.
// grid = (njb j-blocks, 8 b-tiles), block = 4 waves, jpw j's per wave.
// ---------------------------------------------------------------------------
__global__ __launch_bounds__(256, 4) void k_main(
    const float* __restrict__ x, const int* __restrict__ mask,
    const unsigned short* __restrict__ feWb, const float* __restrict__ aux,
    const float* __restrict__ scal,
    const float* __restrict__ hw1, const float* __restrict__ ln1w,
    const float* __restrict__ ln1b,
    const float* __restrict__ hw2, const float* __restrict__ hb2,
    const float* __restrict__ ln2w, const float* __restrict__ ln2b,
    const float* __restrict__ gw1, const float* __restrict__ gb1,
    const float* __restrict__ gw2, const float* __restrict__ gb2,
    float* __restrict__ P, float* __restrict__ SEb, int njb, int jpw)
{
    __shared__ float w0s[128], g1s[128], b1s[128];
    __shared__ float holds[8][576];   // [wave*2+parity][16 rows x pitch 36]
    __shared__ float hsL[2048];
    __shared__ float seL[64];

    const int tid = threadIdx.x, l = tid & 63;
    const int wv = __builtin_amdgcn_readfirstlane(tid >> 6);
    const int c = l & 15, g = l >> 4;
    const int bt = blockIdx.y, bx = blockIdx.x;
    const int b0 = bt * 16;

    if (tid < 128) { w0s[tid] = hw1[tid]; g1s[tid] = ln1w[tid]; b1s[tid] = ln1b[tid]; }
    __syncthreads();

    const float mw0 = scal[0], q0 = scal[1];

    // B-fragments of h_w2 (K=128 -> 4 k-tiles; N=32 -> 2 n-tiles).
    s8x wf[2][4];
#pragma unroll
    for (int nt = 0; nt < 2; ++nt)
#pragma unroll
        for (int t = 0; t < 4; ++t) {
            const int kb = 32 * t + 8 * g, n = 16 * nt + c;
            uint4 u;
            u.x = pkbf(hw2[(kb + 0) * 32 + n], hw2[(kb + 1) * 32 + n]);
            u.y = pkbf(hw2[(kb + 2) * 32 + n], hw2[(kb + 3) * 32 + n]);
            u.z = pkbf(hw2[(kb + 4) * 32 + n], hw2[(kb + 5) * 32 + n]);
            u.w = pkbf(hw2[(kb + 6) * 32 + n], hw2[(kb + 7) * 32 + n]);
            wf[nt][t] = __builtin_bit_cast(s8x, u);
        }
    // B-fragment of g_w1 (32x16): k = 8g+i, col m = c.
    s8x g1f;
    {
        uint4 u;
        u.x = pkbf(gw1[(8 * g + 0) * 16 + c], gw1[(8 * g + 1) * 16 + c]);
        u.y = pkbf(gw1[(8 * g + 2) * 16 + c], gw1[(8 * g + 3) * 16 + c]);
        u.z = pkbf(gw1[(8 * g + 4) * 16 + c], gw1[(8 * g + 5) * 16 + c]);
        u.w = pkbf(gw1[(8 * g + 6) * 16 + c], gw1[(8 * g + 7) * 16 + c]);
        g1f = __builtin_bit_cast(s8x, u);
    }
    const float hb2a = hb2[c],      hb2b = hb2[16 + c];
    const float g2a  = ln2w[c],     g2b  = ln2w[16 + c];
    const float z2a  = ln2b[c],     z2b  = ln2b[16 + c];
    const float gb1c = gb1[c];
    float gw2c[4], gb2v[4];
#pragma unroll
    for (int w = 0; w < 4; ++w) { gw2c[w] = gw2[c * 4 + w]; gb2v[w] = gb2[w]; }

    const int j0 = (bx * 4 + wv) * jpw;
    const float* xrow = x + (size_t)(b0 + c) * JDIM;
    const int*   mrow = mask + (size_t)(b0 + c) * JDIM;

    float hsacc[4][4][2];
    float seacc[4][4];
#pragma unroll
    for (int r = 0; r < 4; ++r)
#pragma unroll
        for (int w = 0; w < 4; ++w) {
            hsacc[r][w][0] = 0.f; hsacc[r][w][1] = 0.f; seacc[r][w] = 0.f;
        }

    for (int jj = 0; jj < jpw; ++jj) {
        const int j = j0 + jj;
        const float xv = xrow[j];
        const int   mv = mrow[j];
        const float4 au = *(const float4*)(aux + j * 4);
        const float m1 = au.x, qx = au.y, q2 = au.z;
        const float mu = fmaf(xv, mw0, m1);
        const float e2 = fmaf(xv * xv, q0, fmaf(2.f * xv, qx, q2));
        const float rs = rsqrtf(e2 - mu * mu + 1e-5f);
        const float nms = -mu * rs;

        f4x ca = {0.f, 0.f, 0.f, 0.f}, cbv = {0.f, 0.f, 0.f, 0.f};
        const unsigned short* fj = feWb + (size_t)j * 128;
#pragma unroll
        for (int t = 0; t < 4; ++t) {
            const int kb = 32 * t + 8 * g;
            const uint4 fw = *(const uint4*)(fj + kb);
            const float pf0 = bf2f(fw.x & 0xffffu), pf1 = bf2f(fw.x >> 16);
            const float pf2 = bf2f(fw.y & 0xffffu), pf3 = bf2f(fw.y >> 16);
            const float pf4 = bf2f(fw.z & 0xffffu), pf5 = bf2f(fw.z >> 16);
            const float pf6 = bf2f(fw.w & 0xffffu), pf7 = bf2f(fw.w >> 16);
            const float4 wa = *(const float4*)&w0s[kb];
            const float4 wb = *(const float4*)&w0s[kb + 4];
            const float4 ga = *(const float4*)&g1s[kb];
            const float4 gbq = *(const float4*)&g1s[kb + 4];
            const float4 ba = *(const float4*)&b1s[kb];
            const float4 bb = *(const float4*)&b1s[kb + 4];
            const float h0 = fmaxf(fmaf(fmaf(fmaf(xv, wa.x, pf0), rs, nms), ga.x,  ba.x), 0.f);
            const float h1 = fmaxf(fmaf(fmaf(fmaf(xv, wa.y, pf1), rs, nms), ga.y,  ba.y), 0.f);
            const float h2 = fmaxf(fmaf(fmaf(fmaf(xv, wa.z, pf2), rs, nms), ga.z,  ba.z), 0.f);
            const float h3 = fmaxf(fmaf(fmaf(fmaf(xv, wa.w, pf3), rs, nms), ga.w,  ba.w), 0.f);
            const float h4 = fmaxf(fmaf(fmaf(fmaf(xv, wb.x, pf4), rs, nms), gbq.x, bb.x), 0.f);
            const float h5 = fmaxf(fmaf(fmaf(fmaf(xv, wb.y, pf5), rs, nms), gbq.y, bb.y), 0.f);
            const float h6 = fmaxf(fmaf(fmaf(fmaf(xv, wb.z, pf6), rs, nms), gbq.z, bb.z), 0.f);
            const float h7 = fmaxf(fmaf(fmaf(fmaf(xv, wb.w, pf7), rs, nms), gbq.w, bb.w), 0.f);
            uint4 u;
            u.x = pkbf(h0, h1); u.y = pkbf(h2, h3); u.z = pkbf(h4, h5); u.w = pkbf(h6, h7);
            const s8x af = __builtin_bit_cast(s8x, u);
            ca  = __builtin_amdgcn_mfma_f32_16x16x32_bf16(af, wf[0][t], ca,  0, 0, 0);
            cbv = __builtin_amdgcn_mfma_f32_16x16x32_bf16(af, wf[1][t], cbv, 0, 0, 0);
        }

        // + h_b2, LN over D=32 (row = cell 4g+r across the 16-lane c-group)
        float v0[4], v1[4], sr[4], qr[4];
#pragma unroll
        for (int r = 0; r < 4; ++r) {
            v0[r] = ca[r] + hb2a;
            v1[r] = cbv[r] + hb2b;
            sr[r] = v0[r] + v1[r];
            qr[r] = v0[r] * v0[r] + v1[r] * v1[r];
        }
#pragma unroll
        for (int r = 0; r < 4; ++r) { sr[r] = allred16(sr[r]); qr[r] = allred16(qr[r]); }
        float ho0[4], ho1[4];
#pragma unroll
        for (int r = 0; r < 4; ++r) {
            const float m2  = sr[r] * 0.03125f;
            const float rs2 = rsqrtf(fmaf(qr[r], 0.03125f, -m2 * m2) + 1e-5f);
            const float nm2 = -m2 * rs2;
            ho0[r] = fmaxf(fmaf(fmaf(v0[r], rs2, nm2), g2a, z2a), 0.f);
            ho1[r] = fmaxf(fmaf(fmaf(v1[r], rs2, nm2), g2b, z2b), 0.f);
        }

        // stage h_out into per-wave LDS (ping-pong), transpose-read A-frag
        float* hp = &holds[wv * 2 + (jj & 1)][0];
#pragma unroll
        for (int r = 0; r < 4; ++r) {
            hp[(4 * g + r) * 36 + c]      = ho0[r];
            hp[(4 * g + r) * 36 + 16 + c] = ho1[r];
        }
        asm volatile("s_waitcnt lgkmcnt(0)" ::: "memory");
        const float4 ra  = *(const float4*)&hp[c * 36 + 8 * g];
        const float4 rb2 = *(const float4*)&hp[c * 36 + 8 * g + 4];
        uint4 ua;
        ua.x = pkbf(ra.x, ra.y);  ua.y = pkbf(ra.z, ra.w);
        ua.z = pkbf(rb2.x, rb2.y); ua.w = pkbf(rb2.z, rb2.w);
        const s8x af2 = __builtin_bit_cast(s8x, ua);
        f4x gc = {0.f, 0.f, 0.f, 0.f};
        gc = __builtin_amdgcn_mfma_f32_16x16x32_bf16(af2, g1f, gc, 0, 0, 0);

        // gate2 partials + DPP all-reduce over the 16 m-lanes
        float pw[16];
#pragma unroll
        for (int r = 0; r < 4; ++r) {
            const float g1r = fmaxf(gc[r] + gb1c, 0.f);
#pragma unroll
            for (int w = 0; w < 4; ++w) pw[r * 4 + w] = g1r * gw2c[w];
        }
#pragma unroll
        for (int i = 0; i < 16; ++i) pw[i] = allred16(pw[i]);

        // mask bits via ballot (lanes 0..15 hold cells 0..15)
        const unsigned bm = (unsigned)__ballot(mv > 0);
        float fm[4];
#pragma unroll
        for (int r = 0; r < 4; ++r) fm[r] = (float)((bm >> (4 * g + r)) & 1u);

#pragma unroll
        for (int r = 0; r < 4; ++r)
#pragma unroll
            for (int w = 0; w < 4; ++w) {
                const float lg = fminf(fmaxf(pw[r * 4 + w] + gb2v[w], -10.f), 10.f);
                const float e  = fm[r] * __builtin_amdgcn_exp2f(
                                     fmaf(lg, 1.44269504089f, -14.4269504089f));
                seacc[r][w] += e;
                hsacc[r][w][0] = fmaf(e, ho0[r], hsacc[r][w][0]);
                hsacc[r][w][1] = fmaf(e, ho1[r], hsacc[r][w][1]);
            }
    }

    // combine the 4 waves' partials in LDS (barrier ladder, no atomics)
    for (int ww = 0; ww < 4; ++ww) {
        __syncthreads();
        if (wv == ww) {
#pragma unroll
            for (int r = 0; r < 4; ++r)
#pragma unroll
                for (int w = 0; w < 4; ++w)
#pragma unroll
                    for (int nt = 0; nt < 2; ++nt) {
                        const int idx = ((4 * g + r) * 4 + w) * 32 + c + 16 * nt;
                        if (ww == 0) hsL[idx] = hsacc[r][w][nt];
                        else         hsL[idx] += hsacc[r][w][nt];
                    }
            if (c == 0) {
#pragma unroll
                for (int r = 0; r < 4; ++r)
#pragma unroll
                    for (int w = 0; w < 4; ++w) {
                        const int si = (4 * g + r) * 4 + w;
                        if (ww == 0) seL[si] = seacc[r][w];
                        else         seL[si] += seacc[r][w];
                    }
            }
        }
    }
    __syncthreads();
    const size_t base = ((size_t)bt * njb + bx) * 2048;
    for (int i = tid; i < 2048; i += 256) P[base + i] = hsL[i];
    if (tid < 64) SEb[((size_t)bt * njb + bx) * 64 + tid] = seL[tid];
}

// ---------------------------------------------------------------------------
// Kernel 2: per b: reduce the njb j-block partials, head_sums = hs/sumexp,
// comb = relu(LN(hs @ c_w + c_b)) (zeroed if no unmasked j), then the two
// e-layers with LN + relu, split into mu / logvar.
// ---------------------------------------------------------------------------
__global__ __launch_bounds__(128) void k_tail(
    const float* __restrict__ P, const float* __restrict__ SEb,
    const float* __restrict__ cw, const float* __restrict__ cbv,
    const float* __restrict__ clnw, const float* __restrict__ clnb,
    const float* __restrict__ ew1, const float* __restrict__ eb1,
    const float* __restrict__ l1w, const float* __restrict__ l1b,
    const float* __restrict__ ew2, const float* __restrict__ eb2,
    const float* __restrict__ l2w, const float* __restrict__ l2b,
    float* __restrict__ out, int njb)
{
    const int b = blockIdx.x, t = threadIdx.x;
    const int bt = b >> 4, bi = b & 15;
    __shared__ float hsLs[128], combL[32], hL[256], seW[4], sred[64], red[4];

    const float* Pb = P + (size_t)bt * njb * 2048 + bi * 128;
    float sacc = 0.f;
#pragma unroll 4
    for (int jc = 0; jc < njb; ++jc) sacc += Pb[(size_t)jc * 2048 + t];

    if (t < 64) {
        const int w = t & 3, part = t >> 2;
        float sp = 0.f;
        for (int q = part; q < njb; q += 16)
            sp += SEb[((size_t)bt * njb + q) * 64 + bi * 4 + w];
        sred[t] = sp;
    }
    __syncthreads();
    if (t < 4) {
        float v = 0.f;
#pragma unroll
        for (int sl = 0; sl < 16; ++sl) v += sred[sl * 4 + t];
        seW[t] = v;
    }
    __syncthreads();
    const bool has = seW[0] > 0.f;
    hsLs[t] = has ? sacc / seW[t >> 5] : 0.f;
    __syncthreads();

    if (t < 32) {
        float cv = cbv[t];
#pragma unroll 4
        for (int f = 0; f < 128; ++f) cv = fmaf(hsLs[f], cw[f * 32 + t], cv);
        float s = cv, q = cv * cv;
#pragma unroll
        for (int m = 1; m <= 16; m <<= 1) { s += __shfl_xor(s, m); q += __shfl_xor(q, m); }
        const float mu = s * (1.f / 32.f);
        const float rsg = rsqrtf(fmaf(q, 1.f / 32.f, -mu * mu) + 1e-5f);
        const float v = fmaf(fmaf(cv, rsg, -mu * rsg), clnw[t], clnb[t]);
        combL[t] = has ? fmaxf(v, 0.f) : 0.f;
    }
    __syncthreads();

    float h0 = eb1[t], h1v = eb1[t + 128];
#pragma unroll 4
    for (int d = 0; d < 32; ++d) {
        const float cd = combL[d];
        h0  = fmaf(cd, ew1[d * 256 + t], h0);
        h1v = fmaf(cd, ew1[d * 256 + t + 128], h1v);
    }
    {
        float s = h0 + h1v, q = h0 * h0 + h1v * h1v;
#pragma unroll
        for (int m = 1; m <= 32; m <<= 1) { s += __shfl_xor(s, m); q += __shfl_xor(q, m); }
        const int wv = t >> 6, ln = t & 63;
        if (ln == 0) { red[wv * 2] = s; red[wv * 2 + 1] = q; }
    }
    __syncthreads();
    {
        const float S = red[0] + red[2], Q = red[1] + red[3];
        const float mu1 = S * (1.f / 256.f);
        const float rs1 = rsqrtf(fmaf(Q, 1.f / 256.f, -mu1 * mu1) + 1e-5f);
        hL[t]       = fmaxf(fmaf(fmaf(h0,  rs1, -mu1 * rs1), l1w[t],       l1b[t]),       0.f);
        hL[t + 128] = fmaxf(fmaf(fmaf(h1v, rs1, -mu1 * rs1), l1w[t + 128], l1b[t + 128]), 0.f);
    }
    __syncthreads();

    if (t < 64) {
        float ov = eb2[t];
#pragma unroll 4
        for (int m = 0; m < 256; ++m) ov = fmaf(hL[m], ew2[m * 64 + t], ov);
        float s = ov, q = ov * ov;
#pragma unroll
        for (int m = 1; m <= 32; m <<= 1) { s += __shfl_xor(s, m); q += __shfl_xor(q, m); }
        const float mu2 = s * (1.f / 64.f);
        const float rs2 = rsqrtf(fmaf(q, 1.f / 64.f, -mu2 * mu2) + 1e-5f);
        const float o = fmaxf(fmaf(fmaf(ov, rs2, -mu2 * rs2), l2w[t], l2b[t]), 0.f);
        if (t < 32) out[b * 32 + t] = o;
        else        out[4096 + b * 32 + (t - 32)] = o;
    }
}

// ---------------------------------------------------------------------------
extern "C" void kernel_launch(void* const* d_in, const int* in_sizes, int n_in,
                              void* d_out, int out_size, void* d_ws, size_t ws_size,
                              hipStream_t stream)
{
    (void)in_sizes; (void)n_in; (void)out_size;
    const float* x    = (const float*)d_in[0];
    const int*   mask = (const int*)d_in[1];
    const float* fe   = (const float*)d_in[2];
    const float* hw1  = (const float*)d_in[3];
    const float* hb1  = (const float*)d_in[4];
    const float* ln1w = (const float*)d_in[5];
    const float* ln1b = (const float*)d_in[6];
    const float* hw2  = (const float*)d_in[7];
    const float* hb2  = (const float*)d_in[8];
    const float* ln2w = (const float*)d_in[9];
    const float* ln2b = (const float*)d_in[10];
    const float* gw1  = (const float*)d_in[11];
    const float* gb1  = (const float*)d_in[12];
    const float* gw2  = (const float*)d_in[13];
    const float* gb2  = (const float*)d_in[14];
    const float* cw   = (const float*)d_in[15];
    const float* cbv  = (const float*)d_in[16];
    const float* clnw = (const float*)d_in[17];
    const float* clnb = (const float*)d_in[18];
    const float* ew1  = (const float*)d_in[19];
    const float* eb1  = (const float*)d_in[20];
    const float* l1w  = (const float*)d_in[21];
    const float* l1b  = (const float*)d_in[22];
    const float* ew2  = (const float*)d_in[23];
    const float* eb2  = (const float*)d_in[24];
    const float* l2w  = (const float*)d_in[25];
    const float* l2b  = (const float*)d_in[26];

    const size_t base = (2u << 20) + (128u << 10) + 256u;
    // choose j-split by available workspace (njb=128 preferred for occupancy)
    int NJB = 128;
    {
        const size_t need = base + (size_t)8 * 128 * 2048 * 4 + (size_t)8 * 128 * 64 * 4;
        if (ws_size < need) NJB = 64;
    }
    const int JPW = JDIM / (NJB * 4);

    char* ws = (char*)d_ws;
    unsigned short* feWb = (unsigned short*)ws;                       // 2 MB
    float* aux  = (float*)(ws + (2u << 20));                          // 128 KB
    float* scal = (float*)(ws + (2u << 20) + (128u << 10));           // 256 B
    float* P    = (float*)(ws + base);                                // 8*NJB*2048*4 B
    float* SEb  = (float*)(ws + base + (size_t)8 * NJB * 2048 * 4);   // 8*NJB*64*4 B

    hipLaunchKernelGGL(k_prep, dim3(JDIM), dim3(128), 0, stream,
                       fe, hw1, hb1, feWb, aux, scal);
    hipLaunchKernelGGL(k_main, dim3(NJB, 8), dim3(256), 0, stream,
                       x, mask, feWb, aux, scal,
                       hw1, ln1w, ln1b, hw2, hb2, ln2w, ln2b,
                       gw1, gb1, gw2, gb2, P, SEb, NJB, JPW);
    hipLaunchKernelGGL(k_tail, dim3(BDIM), dim3(128), 0, stream,
                       P, SEb, cw, cbv, clnw, clnb,
                       ew1, eb1, l1w, l1b, ew2, eb2, l2w, l2b,
                       (float*)d_out, NJB);
}

// Round 4
// 256.334 us; speedup vs baseline: 1.1108x; 1.1108x over previous
//
#include <hip/hip_runtime.h>
#include <cstdint>

// Problem constants (reference: B,J,D,W,H,EH,L = 128,8192,32,4,128,256,32)
#define BDIM 128
#define JDIM 8192

typedef short s8x __attribute__((ext_vector_type(8)));   // 8 bf16 in 4 VGPRs (MFMA A/B frag)
typedef float f4x __attribute__((ext_vector_type(4)));   // MFMA C/D frag

__device__ __forceinline__ unsigned int rne16(float f) {
    unsigned int u = __float_as_uint(f);
    return (u + 0x7fffu + ((u >> 16) & 1u)) >> 16;       // round-to-nearest-even bf16
}
__device__ __forceinline__ unsigned int pkbf(float lo, float hi) {
    return rne16(lo) | (rne16(hi) << 16);
}
__device__ __forceinline__ float bf2f(unsigned int s) {
    return __uint_as_float(s << 16);
}

// 16-lane (DPP-row) all-reduce sum: xor1, xor2, ^7, ^15 — pure VALU, no DS pipe.
template <int CTRL>
__device__ __forceinline__ float dppadd(float x) {
    int y = __builtin_amdgcn_update_dpp(0, __builtin_bit_cast(int, x), CTRL, 0xF, 0xF, true);
    return x + __builtin_bit_cast(float, y);
}
__device__ __forceinline__ float allred16(float x) {
    x = dppadd<0xB1>(x);    // quad_perm [1,0,3,2]  : lane ^ 1
    x = dppadd<0x4E>(x);    // quad_perm [2,3,0,1]  : lane ^ 2
    x = dppadd<0x141>(x);   // row_half_mirror      : lane ^ 7
    x = dppadd<0x140>(x);   // row_mirror           : lane ^ 15
    return x;
}

// ---------------------------------------------------------------------------
// Kernel 0: feW[j][h] = fe[j,:] @ h_w1[1:,:] + h_b1  (stored bf16), plus per-j
// moments for closed-form LN1 stats; block j==0 writes mean(w0), mean(w0^2).
// ---------------------------------------------------------------------------
__global__ __launch_bounds__(128) void k_prep(
    const float* __restrict__ fe, const float* __restrict__ hw1,
    const float* __restrict__ hb1,
    unsigned short* __restrict__ feWb, float* __restrict__ aux,
    float* __restrict__ scal)
{
    const int j = blockIdx.x, h = threadIdx.x;
    float acc = hb1[h];
#pragma unroll
    for (int d = 0; d < 32; ++d)
        acc = fmaf(fe[j * 32 + d], hw1[(1 + d) * 128 + h], acc);
    feWb[(size_t)j * 128 + h] = (unsigned short)rne16(acc);

    const float w0h = hw1[h];
    float s1 = acc, sx = w0h * acc, s2 = acc * acc;
#pragma unroll
    for (int m = 1; m <= 32; m <<= 1) {
        s1 += __shfl_xor(s1, m); sx += __shfl_xor(sx, m); s2 += __shfl_xor(s2, m);
    }
    __shared__ float red[2][3];
    const int wv = threadIdx.x >> 6, ln = threadIdx.x & 63;
    if (ln == 0) { red[wv][0] = s1; red[wv][1] = sx; red[wv][2] = s2; }
    __syncthreads();
    if (threadIdx.x == 0) {
        aux[j * 4 + 0] = (red[0][0] + red[1][0]) * (1.f / 128.f);
        aux[j * 4 + 1] = (red[0][1] + red[1][1]) * (1.f / 128.f);
        aux[j * 4 + 2] = (red[0][2] + red[1][2]) * (1.f / 128.f);
    }
    if (j == 0) {
        float a = w0h, b = w0h * w0h;
#pragma unroll
        for (int m = 1; m <= 32; m <<= 1) { a += __shfl_xor(a, m); b += __shfl_xor(b, m); }
        __syncthreads();
        if (ln == 0) { red[wv][0] = a; red[wv][1] = b; }
        __syncthreads();
        if (threadIdx.x == 0) {
            scal[0] = (red[0][0] + red[1][0]) * (1.f / 128.f);
            scal[1] = (red[0][1] + red[1][1]) * (1.f / 128.f);
        }
    }
}

// ---------------------------------------------------------------------------
// Kernel 1: per cell (b,j): pre -> LN1 -> relu -> (MFMA) @h_w2 -> +b2 -> LN2
// -> relu -> gates (MFMA + DPP all-reduce) -> exp(logit-10) -> weighted
// accumulation of head_sums in registers.  Wave = 1 j x 16 b.
// grid = (njb j-blocks, 8 b-tiles), block = 4 waves, jpw j's per wave.
// NOTE: (256,2) not (256,4): the 4-waves/EU bound caps VGPRs at 64 and the
// allocator spills wf/hsacc into scratch (R3: FETCH 5.4MB->343MB). At (256,2)
// the kernel fits in 128 VGPR -> 4 blocks/CU resident with the 1024-block grid.
// ---------------------------------------------------------------------------
__global__ __launch_bounds__(256, 2) void k_main(
    const float* __restrict__ x, const int* __restrict__ mask,
    const unsigned short* __restrict__ feWb, const float* __restrict__ aux,
    const float* __restrict__ scal,
    const float* __restrict__ hw1, const float* __restrict__ ln1w,
    const float* __restrict__ ln1b,
    const float* __restrict__ hw2, const float* __restrict__ hb2,
    const float* __restrict__ ln2w, const float* __restrict__ ln2b,
    const float* __restrict__ gw1, const float* __restrict__ gb1,
    const float* __restrict__ gw2, const float* __restrict__ gb2,
    float* __restrict__ P, float* __restrict__ SEb, int njb, int jpw)
{
    __shared__ float w0s[128], g1s[128], b1s[128];
    __shared__ float holds[8][576];   // [wave*2+parity][16 rows x pitch 36]
    __shared__ float hsL[2048];
    __shared__ float seL[64];

    const int tid = threadIdx.x, l = tid & 63;
    const int wv = __builtin_amdgcn_readfirstlane(tid >> 6);
    const int c = l & 15, g = l >> 4;
    const int bt = blockIdx.y, bx = blockIdx.x;
    const int b0 = bt * 16;

    if (tid < 128) { w0s[tid] = hw1[tid]; g1s[tid] = ln1w[tid]; b1s[tid] = ln1b[tid]; }
    __syncthreads();

    const float mw0 = scal[0], q0 = scal[1];

    // B-fragments of h_w2 (K=128 -> 4 k-tiles; N=32 -> 2 n-tiles).
    s8x wf[2][4];
#pragma unroll
    for (int nt = 0; nt < 2; ++nt)
#pragma unroll
        for (int t = 0; t < 4; ++t) {
            const int kb = 32 * t + 8 * g, n = 16 * nt + c;
            uint4 u;
            u.x = pkbf(hw2[(kb + 0) * 32 + n], hw2[(kb + 1) * 32 + n]);
            u.y = pkbf(hw2[(kb + 2) * 32 + n], hw2[(kb + 3) * 32 + n]);
            u.z = pkbf(hw2[(kb + 4) * 32 + n], hw2[(kb + 5) * 32 + n]);
            u.w = pkbf(hw2[(kb + 6) * 32 + n], hw2[(kb + 7) * 32 + n]);
            wf[nt][t] = __builtin_bit_cast(s8x, u);
        }
    // B-fragment of g_w1 (32x16): k = 8g+i, col m = c.
    s8x g1f;
    {
        uint4 u;
        u.x = pkbf(gw1[(8 * g + 0) * 16 + c], gw1[(8 * g + 1) * 16 + c]);
        u.y = pkbf(gw1[(8 * g + 2) * 16 + c], gw1[(8 * g + 3) * 16 + c]);
        u.z = pkbf(gw1[(8 * g + 4) * 16 + c], gw1[(8 * g + 5) * 16 + c]);
        u.w = pkbf(gw1[(8 * g + 6) * 16 + c], gw1[(8 * g + 7) * 16 + c]);
        g1f = __builtin_bit_cast(s8x, u);
    }
    const float hb2a = hb2[c],      hb2b = hb2[16 + c];
    const float g2a  = ln2w[c],     g2b  = ln2w[16 + c];
    const float z2a  = ln2b[c],     z2b  = ln2b[16 + c];
    const float gb1c = gb1[c];
    float gw2c[4], gb2v[4];
#pragma unroll
    for (int w = 0; w < 4; ++w) { gw2c[w] = gw2[c * 4 + w]; gb2v[w] = gb2[w]; }

    const int j0 = (bx * 4 + wv) * jpw;
    const float* xrow = x + (size_t)(b0 + c) * JDIM;
    const int*   mrow = mask + (size_t)(b0 + c) * JDIM;

    float hsacc[4][4][2];
    float seacc[4][4];
#pragma unroll
    for (int r = 0; r < 4; ++r)
#pragma unroll
        for (int w = 0; w < 4; ++w) {
            hsacc[r][w][0] = 0.f; hsacc[r][w][1] = 0.f; seacc[r][w] = 0.f;
        }

    for (int jj = 0; jj < jpw; ++jj) {
        const int j = j0 + jj;
        const float xv = xrow[j];
        const int   mv = mrow[j];
        const float4 au = *(const float4*)(aux + j * 4);
        const float m1 = au.x, qx = au.y, q2 = au.z;
        const float mu = fmaf(xv, mw0, m1);
        const float e2 = fmaf(xv * xv, q0, fmaf(2.f * xv, qx, q2));
        const float rs = rsqrtf(e2 - mu * mu + 1e-5f);
        const float nms = -mu * rs;

        f4x ca = {0.f, 0.f, 0.f, 0.f}, cbv = {0.f, 0.f, 0.f, 0.f};
        const unsigned short* fj = feWb + (size_t)j * 128;
#pragma unroll
        for (int t = 0; t < 4; ++t) {
            const int kb = 32 * t + 8 * g;
            const uint4 fw = *(const uint4*)(fj + kb);
            const float pf0 = bf2f(fw.x & 0xffffu), pf1 = bf2f(fw.x >> 16);
            const float pf2 = bf2f(fw.y & 0xffffu), pf3 = bf2f(fw.y >> 16);
            const float pf4 = bf2f(fw.z & 0xffffu), pf5 = bf2f(fw.z >> 16);
            const float pf6 = bf2f(fw.w & 0xffffu), pf7 = bf2f(fw.w >> 16);
            const float4 wa = *(const float4*)&w0s[kb];
            const float4 wb = *(const float4*)&w0s[kb + 4];
            const float4 ga = *(const float4*)&g1s[kb];
            const float4 gbq = *(const float4*)&g1s[kb + 4];
            const float4 ba = *(const float4*)&b1s[kb];
            const float4 bb = *(const float4*)&b1s[kb + 4];
            const float h0 = fmaxf(fmaf(fmaf(fmaf(xv, wa.x, pf0), rs, nms), ga.x,  ba.x), 0.f);
            const float h1 = fmaxf(fmaf(fmaf(fmaf(xv, wa.y, pf1), rs, nms), ga.y,  ba.y), 0.f);
            const float h2 = fmaxf(fmaf(fmaf(fmaf(xv, wa.z, pf2), rs, nms), ga.z,  ba.z), 0.f);
            const float h3 = fmaxf(fmaf(fmaf(fmaf(xv, wa.w, pf3), rs, nms), ga.w,  ba.w), 0.f);
            const float h4 = fmaxf(fmaf(fmaf(fmaf(xv, wb.x, pf4), rs, nms), gbq.x, bb.x), 0.f);
            const float h5 = fmaxf(fmaf(fmaf(fmaf(xv, wb.y, pf5), rs, nms), gbq.y, bb.y), 0.f);
            const float h6 = fmaxf(fmaf(fmaf(fmaf(xv, wb.z, pf6), rs, nms), gbq.z, bb.z), 0.f);
            const float h7 = fmaxf(fmaf(fmaf(fmaf(xv, wb.w, pf7), rs, nms), gbq.w, bb.w), 0.f);
            uint4 u;
            u.x = pkbf(h0, h1); u.y = pkbf(h2, h3); u.z = pkbf(h4, h5); u.w = pkbf(h6, h7);
            const s8x af = __builtin_bit_cast(s8x, u);
            ca  = __builtin_amdgcn_mfma_f32_16x16x32_bf16(af, wf[0][t], ca,  0, 0, 0);
            cbv = __builtin_amdgcn_mfma_f32_16x16x32_bf16(af, wf[1][t], cbv, 0, 0, 0);
        }

        // + h_b2, LN over D=32 (row = cell 4g+r across the 16-lane c-group)
        float v0[4], v1[4], sr[4], qr[4];
#pragma unroll
        for (int r = 0; r < 4; ++r) {
            v0[r] = ca[r] + hb2a;
            v1[r] = cbv[r] + hb2b;
            sr[r] = v0[r] + v1[r];
            qr[r] = v0[r] * v0[r] + v1[r] * v1[r];
        }
#pragma unroll
        for (int r = 0; r < 4; ++r) { sr[r] = allred16(sr[r]); qr[r] = allred16(qr[r]); }
        float ho0[4], ho1[4];
#pragma unroll
        for (int r = 0; r < 4; ++r) {
            const float m2  = sr[r] * 0.03125f;
            const float rs2 = rsqrtf(fmaf(qr[r], 0.03125f, -m2 * m2) + 1e-5f);
            const float nm2 = -m2 * rs2;
            ho0[r] = fmaxf(fmaf(fmaf(v0[r], rs2, nm2), g2a, z2a), 0.f);
            ho1[r] = fmaxf(fmaf(fmaf(v1[r], rs2, nm2), g2b, z2b), 0.f);
        }

        // stage h_out into per-wave LDS (ping-pong), transpose-read A-frag
        float* hp = &holds[wv * 2 + (jj & 1)][0];
#pragma unroll
        for (int r = 0; r < 4; ++r) {
            hp[(4 * g + r) * 36 + c]      = ho0[r];
            hp[(4 * g + r) * 36 + 16 + c] = ho1[r];
        }
        asm volatile("s_waitcnt lgkmcnt(0)" ::: "memory");
        const float4 ra  = *(const float4*)&hp[c * 36 + 8 * g];
        const float4 rb2 = *(const float4*)&hp[c * 36 + 8 * g + 4];
        uint4 ua;
        ua.x = pkbf(ra.x, ra.y);  ua.y = pkbf(ra.z, ra.w);
        ua.z = pkbf(rb2.x, rb2.y); ua.w = pkbf(rb2.z, rb2.w);
        const s8x af2 = __builtin_bit_cast(s8x, ua);
        f4x gc = {0.f, 0.f, 0.f, 0.f};
        gc = __builtin_amdgcn_mfma_f32_16x16x32_bf16(af2, g1f, gc, 0, 0, 0);

        // gate2 partials + DPP all-reduce over the 16 m-lanes
        float pw[16];
#pragma unroll
        for (int r = 0; r < 4; ++r) {
            const float g1r = fmaxf(gc[r] + gb1c, 0.f);
#pragma unroll
            for (int w = 0; w < 4; ++w) pw[r * 4 + w] = g1r * gw2c[w];
        }
#pragma unroll
        for (int i = 0; i < 16; ++i) pw[i] = allred16(pw[i]);

        // mask bits via ballot (lanes 0..15 hold cells 0..15)
        const unsigned bm = (unsigned)__ballot(mv > 0);
        float fm[4];
#pragma unroll
        for (int r = 0; r < 4; ++r) fm[r] = (float)((bm >> (4 * g + r)) & 1u);

#pragma unroll
        for (int r = 0; r < 4; ++r)
#pragma unroll
            for (int w = 0; w < 4; ++w) {
                const float lg = fminf(fmaxf(pw[r * 4 + w] + gb2v[w], -10.f), 10.f);
                const float e  = fm[r] * __builtin_amdgcn_exp2f(
                                     fmaf(lg, 1.44269504089f, -14.4269504089f));
                seacc[r][w] += e;
                hsacc[r][w][0] = fmaf(e, ho0[r], hsacc[r][w][0]);
                hsacc[r][w][1] = fmaf(e, ho1[r], hsacc[r][w][1]);
            }
    }

    // combine the 4 waves' partials in LDS (barrier ladder, no atomics)
    for (int ww = 0; ww < 4; ++ww) {
        __syncthreads();
        if (wv == ww) {
#pragma unroll
            for (int r = 0; r < 4; ++r)
#pragma unroll
                for (int w = 0; w < 4; ++w)
#pragma unroll
                    for (int nt = 0; nt < 2; ++nt) {
                        const int idx = ((4 * g + r) * 4 + w) * 32 + c + 16 * nt;
                        if (ww == 0) hsL[idx] = hsacc[r][w][nt];
                        else         hsL[idx] += hsacc[r][w][nt];
                    }
            if (c == 0) {
#pragma unroll
                for (int r = 0; r < 4; ++r)
#pragma unroll
                    for (int w = 0; w < 4; ++w) {
                        const int si = (4 * g + r) * 4 + w;
                        if (ww == 0) seL[si] = seacc[r][w];
                        else         seL[si] += seacc[r][w];
                    }
            }
        }
    }
    __syncthreads();
    const size_t base = ((size_t)bt * njb + bx) * 2048;
    for (int i = tid; i < 2048; i += 256) P[base + i] = hsL[i];
    if (tid < 64) SEb[((size_t)bt * njb + bx) * 64 + tid] = seL[tid];
}

// ---------------------------------------------------------------------------
// Kernel 2: per b: reduce the njb j-block partials, head_sums = hs/sumexp,
// comb = relu(LN(hs @ c_w + c_b)) (zeroed if no unmasked j), then the two
// e-layers with LN + relu, split into mu / logvar.
// ---------------------------------------------------------------------------
__global__ __launch_bounds__(128) void k_tail(
    const float* __restrict__ P, const float* __restrict__ SEb,
    const float* __restrict__ cw, const float* __restrict__ cbv,
    const float* __restrict__ clnw, const float* __restrict__ clnb,
    const float* __restrict__ ew1, const float* __restrict__ eb1,
    const float* __restrict__ l1w, const float* __restrict__ l1b,
    const float* __restrict__ ew2, const float* __restrict__ eb2,
    const float* __restrict__ l2w, const float* __restrict__ l2b,
    float* __restrict__ out, int njb)
{
    const int b = blockIdx.x, t = threadIdx.x;
    const int bt = b >> 4, bi = b & 15;
    __shared__ float hsLs[128], combL[32], hL[256], seW[4], sred[64], red[4];

    const float* Pb = P + (size_t)bt * njb * 2048 + bi * 128;
    float sacc = 0.f;
#pragma unroll 4
    for (int jc = 0; jc < njb; ++jc) sacc += Pb[(size_t)jc * 2048 + t];

    if (t < 64) {
        const int w = t & 3, part = t >> 2;
        float sp = 0.f;
        for (int q = part; q < njb; q += 16)
            sp += SEb[((size_t)bt * njb + q) * 64 + bi * 4 + w];
        sred[t] = sp;
    }
    __syncthreads();
    if (t < 4) {
        float v = 0.f;
#pragma unroll
        for (int sl = 0; sl < 16; ++sl) v += sred[sl * 4 + t];
        seW[t] = v;
    }
    __syncthreads();
    const bool has = seW[0] > 0.f;
    hsLs[t] = has ? sacc / seW[t >> 5] : 0.f;
    __syncthreads();

    if (t < 32) {
        float cv = cbv[t];
#pragma unroll 4
        for (int f = 0; f < 128; ++f) cv = fmaf(hsLs[f], cw[f * 32 + t], cv);
        float s = cv, q = cv * cv;
#pragma unroll
        for (int m = 1; m <= 16; m <<= 1) { s += __shfl_xor(s, m); q += __shfl_xor(q, m); }
        const float mu = s * (1.f / 32.f);
        const float rsg = rsqrtf(fmaf(q, 1.f / 32.f, -mu * mu) + 1e-5f);
        const float v = fmaf(fmaf(cv, rsg, -mu * rsg), clnw[t], clnb[t]);
        combL[t] = has ? fmaxf(v, 0.f) : 0.f;
    }
    __syncthreads();

    float h0 = eb1[t], h1v = eb1[t + 128];
#pragma unroll 4
    for (int d = 0; d < 32; ++d) {
        const float cd = combL[d];
        h0  = fmaf(cd, ew1[d * 256 + t], h0);
        h1v = fmaf(cd, ew1[d * 256 + t + 128], h1v);
    }
    {
        float s = h0 + h1v, q = h0 * h0 + h1v * h1v;
#pragma unroll
        for (int m = 1; m <= 32; m <<= 1) { s += __shfl_xor(s, m); q += __shfl_xor(q, m); }
        const int wv = t >> 6, ln = t & 63;
        if (ln == 0) { red[wv * 2] = s; red[wv * 2 + 1] = q; }
    }
    __syncthreads();
    {
        const float S = red[0] + red[2], Q = red[1] + red[3];
        const float mu1 = S * (1.f / 256.f);
        const float rs1 = rsqrtf(fmaf(Q, 1.f / 256.f, -mu1 * mu1) + 1e-5f);
        hL[t]       = fmaxf(fmaf(fmaf(h0,  rs1, -mu1 * rs1), l1w[t],       l1b[t]),       0.f);
        hL[t + 128] = fmaxf(fmaf(fmaf(h1v, rs1, -mu1 * rs1), l1w[t + 128], l1b[t + 128]), 0.f);
    }
    __syncthreads();

    if (t < 64) {
        float ov = eb2[t];
#pragma unroll 4
        for (int m = 0; m < 256; ++m) ov = fmaf(hL[m], ew2[m * 64 + t], ov);
        float s = ov, q = ov * ov;
#pragma unroll
        for (int m = 1; m <= 32; m <<= 1) { s += __shfl_xor(s, m); q += __shfl_xor(q, m); }
        const float mu2 = s * (1.f / 64.f);
        const float rs2 = rsqrtf(fmaf(q, 1.f / 64.f, -mu2 * mu2) + 1e-5f);
        const float o = fmaxf(fmaf(fmaf(ov, rs2, -mu2 * rs2), l2w[t], l2b[t]), 0.f);
        if (t < 32) out[b * 32 + t] = o;
        else        out[4096 + b * 32 + (t - 32)] = o;
    }
}

// ---------------------------------------------------------------------------
extern "C" void kernel_launch(void* const* d_in, const int* in_sizes, int n_in,
                              void* d_out, int out_size, void* d_ws, size_t ws_size,
                              hipStream_t stream)
{
    (void)in_sizes; (void)n_in; (void)out_size;
    const float* x    = (const float*)d_in[0];
    const int*   mask = (const int*)d_in[1];
    const float* fe   = (const float*)d_in[2];
    const float* hw1  = (const float*)d_in[3];
    const float* hb1  = (const float*)d_in[4];
    const float* ln1w = (const float*)d_in[5];
    const float* ln1b = (const float*)d_in[6];
    const float* hw2  = (const float*)d_in[7];
    const float* hb2  = (const float*)d_in[8];
    const float* ln2w = (const float*)d_in[9];
    const float* ln2b = (const float*)d_in[10];
    const float* gw1  = (const float*)d_in[11];
    const float* gb1  = (const float*)d_in[12];
    const float* gw2  = (const float*)d_in[13];
    const float* gb2  = (const float*)d_in[14];
    const float* cw   = (const float*)d_in[15];
    const float* cbv  = (const float*)d_in[16];
    const float* clnw = (const float*)d_in[17];
    const float* clnb = (const float*)d_in[18];
    const float* ew1  = (const float*)d_in[19];
    const float* eb1  = (const float*)d_in[20];
    const float* l1w  = (const float*)d_in[21];
    const float* l1b  = (const float*)d_in[22];
    const float* ew2  = (const float*)d_in[23];
    const float* eb2  = (const float*)d_in[24];
    const float* l2w  = (const float*)d_in[25];
    const float* l2b  = (const float*)d_in[26];

    const size_t base = (2u << 20) + (128u << 10) + 256u;
    // choose j-split by available workspace (njb=128 preferred for occupancy)
    int NJB = 128;
    {
        const size_t need = base + (size_t)8 * 128 * 2048 * 4 + (size_t)8 * 128 * 64 * 4;
        if (ws_size < need) NJB = 64;
    }
    const int JPW = JDIM / (NJB * 4);

    char* ws = (char*)d_ws;
    unsigned short* feWb = (unsigned short*)ws;                       // 2 MB
    float* aux  = (float*)(ws + (2u << 20));                          // 128 KB
    float* scal = (float*)(ws + (2u << 20) + (128u << 10));           // 256 B
    float* P    = (float*)(ws + base);                                // 8*NJB*2048*4 B
    float* SEb  = (float*)(ws + base + (size_t)8 * NJB * 2048 * 4);   // 8*NJB*64*4 B

    hipLaunchKernelGGL(k_prep, dim3(JDIM), dim3(128), 0, stream,
                       fe, hw1, hb1, feWb, aux, scal);
    hipLaunchKernelGGL(k_main, dim3(NJB, 8), dim3(256), 0, stream,
                       x, mask, feWb, aux, scal,
                       hw1, ln1w, ln1b, hw2, hb2, ln2w, ln2b,
                       gw1, gb1, gw2, gb2, P, SEb, NJB, JPW);
    hipLaunchKernelGGL(k_tail, dim3(BDIM), dim3(128), 0, stream,
                       P, SEb, cw, cbv, clnw, clnb,
                       ew1, eb1, l1w, l1b, ew2, eb2, l2w, l2b,
                       (float*)d_out, NJB);
}